// Round 12
// baseline (48.560 us; speedup 1.0000x reference)
//
#include <hip/hip_runtime.h>

typedef float f4 __attribute__((ext_vector_type(4)));

// out[row][c] = x[row][c] + pe[row - seg_start(row)][c]
// FAST PATH (taken by this input): if all dia_len == L and L divides the
// grid-stride in rows, each thread's pos-within-segment is constant ->
// pe is ONE hoisted register load and the loop is load/add/nt-store.
// GENERIC PATH: R11 prologue (wave shfl scan + bucket table) + lookup.
__global__ void __launch_bounds__(512)
pe_fused_kernel(const f4* __restrict__ x,
                const f4* __restrict__ pe,
                const int* __restrict__ dia_len, int n_seg,
                f4* __restrict__ out, long n4, int n_rows) {
    __shared__ int ex[513];      // exclusive cumsum (generic path)
    __shared__ int seg_lo[512];  // bucket b -> segment containing row b*64
    __shared__ int wshare[8];    // ballot flags / wave sums
    const int t    = threadIdx.x;
    const int lane = t & 63;
    const int wid  = t >> 6;

    const long stride = (long)gridDim.x * blockDim.x;
    long i = (long)blockIdx.x * blockDim.x + t;
    const int col = (int)(i & 255);   // constant per thread (stride % 256 == 0)

    // --- uniformity check: all dia_len equal? (1 ballot + 1 barrier) ---
    const int L0 = dia_len[0];
    const int myok = (t < n_seg) ? (dia_len[t] == L0) : 1;
    const unsigned long long ball = __ballot(myok);
    if (lane == 0) wshare[wid] = (ball == ~0ull);
    __syncthreads();
    int uni = 1;
    #pragma unroll
    for (int w = 0; w < 8; ++w) uni &= wshare[w];

    const int srows = (int)(stride >> 8);           // grid-stride in rows
    const bool fast = uni && L0 > 0 && ((stride & 255) == 0)
                      && (srows % L0 == 0)
                      && ((long)n_seg * L0 >= n_rows);

    if (fast) {
        // pos constant per thread: row = row0 + srows*k, srows % L0 == 0
        const int p = (int)((i >> 8) % L0);
        const f4 pv = pe[((long)p << 8) | col];
        for (; i + 3 * stride < n4; i += 4 * stride) {
            const f4 a0 = x[i];
            const f4 a1 = x[i + stride];
            const f4 a2 = x[i + 2 * stride];
            const f4 a3 = x[i + 3 * stride];
            __builtin_nontemporal_store(a0 + pv, &out[i]);
            __builtin_nontemporal_store(a1 + pv, &out[i + stride]);
            __builtin_nontemporal_store(a2 + pv, &out[i + 2 * stride]);
            __builtin_nontemporal_store(a3 + pv, &out[i + 3 * stride]);
        }
        for (; i < n4; i += stride)
            __builtin_nontemporal_store(x[i] + pv, &out[i]);
        return;
    }

    // --- generic path: wave shfl scan prologue + bucket lookup ---
    const int v = (t < n_seg) ? dia_len[t] : 0;
    int scan = v;
    #pragma unroll
    for (int off = 1; off < 64; off <<= 1) {
        const int u = __shfl_up(scan, off, 64);
        if (lane >= off) scan += u;
    }
    __syncthreads();             // wshare reuse: ballot flags -> wave sums
    if (lane == 63) wshare[wid] = scan;
    __syncthreads();
    int pre = 0;
    #pragma unroll
    for (int w = 0; w < 8; ++w) pre += (w < wid) ? wshare[w] : 0;
    ex[t + 1] = scan + pre;
    if (t == 0) ex[0] = 0;
    __syncthreads();
    if (t < n_seg) {
        const int st = ex[t], en = ex[t + 1];
        for (int b = (st + 63) >> 6; (b << 6) < en; ++b) seg_lo[b] = t;
    }
    __syncthreads();

    #define PE_POS(ROW, P)                                            \
        int P;                                                        \
        {                                                             \
            int s_ = seg_lo[(ROW) >> 6];                              \
            while (ex[s_ + 1] <= (ROW)) ++s_;                         \
            P = (ROW) - ex[s_];                                       \
        }

    int p_cur = -1;
    f4 pv;
    #define PE_GET(P, B)                                              \
        if ((P) != p_cur) { p_cur = (P); pv = pe[((long)p_cur << 8) | col]; } \
        const f4 B = pv;

    for (; i + 3 * stride < n4; i += 4 * stride) {
        const long i0 = i, i1 = i + stride, i2 = i + 2 * stride, i3 = i + 3 * stride;
        const f4 a0 = x[i0], a1 = x[i1], a2 = x[i2], a3 = x[i3];
        const int r0 = (int)(i0 >> 8), r1 = (int)(i1 >> 8),
                  r2 = (int)(i2 >> 8), r3 = (int)(i3 >> 8);
        PE_POS(r0, p0) PE_POS(r1, p1) PE_POS(r2, p2) PE_POS(r3, p3)
        PE_GET(p0, b0)
        __builtin_nontemporal_store(a0 + b0, &out[i0]);
        PE_GET(p1, b1)
        __builtin_nontemporal_store(a1 + b1, &out[i1]);
        PE_GET(p2, b2)
        __builtin_nontemporal_store(a2 + b2, &out[i2]);
        PE_GET(p3, b3)
        __builtin_nontemporal_store(a3 + b3, &out[i3]);
    }
    for (; i < n4; i += stride) {
        const int row = (int)(i >> 8);
        PE_POS(row, p)
        PE_GET(p, b)
        const f4 a = x[i];
        __builtin_nontemporal_store(a + b, &out[i]);
    }
    #undef PE_POS
    #undef PE_GET
}

extern "C" void kernel_launch(void* const* d_in, const int* in_sizes, int n_in,
                              void* d_out, int out_size, void* d_ws, size_t ws_size,
                              hipStream_t stream) {
    const float* x  = (const float*)d_in[0];
    const float* pe = (const float*)d_in[1];
    const int*   dl = (const int*)d_in[2];

    const int n_seg  = in_sizes[2];          // 512 (<= 512 for LDS tables)
    const int n_rows = out_size / 1024;      // 32768 rows (D_MODEL = 1024)
    const long n4 = (long)out_size / 4;      // 8,388,608 f4 -> 16 per thread

    pe_fused_kernel<<<1024, 512, 0, stream>>>(
        (const f4*)x, (const f4*)pe, dl, n_seg, (f4*)d_out, n4, n_rows);
}

// Round 13
// 47.172 us; speedup vs baseline: 1.0294x; 1.0294x over previous
//
#include <hip/hip_runtime.h>

typedef float f4 __attribute__((ext_vector_type(4)));

// out[row][c] = x[row][c] + pe[row - seg_start(row)][c]
// Final config (best measured: R11, 46.34 us = 5.78 TB/s effective, 92%
// of the 6.29 TB/s copy ceiling for the same 1-read:1-write mix):
//  - grid-stride streaming layout: 1024 x 512, stride = 2048 rows ->
//    per-thread column and pos-within-segment are loop-invariant for
//    uniform-64 segments
//  - pe cached in ONE register, reloaded only when pos changes
//    (arbitrary dia_len stays correct via the bucket-table lookup)
//  - nt-stores for out (best cache policy, R5); plain loads for x
//    (L3 retention helps, R6)
//  - cheap prologue: wave shfl scan, 3 barriers (R11)
// Ruled out by experiment: batched loads/sched_barrier/SW-pipeline (MLP
// not the limiter, R4/R5/R7), nt-loads (R6), stride-64 traversal (R9),
// copy-shaped fast path (R12: instruction stream not the limiter).
__global__ void __launch_bounds__(512)
pe_fused_kernel(const f4* __restrict__ x,
                const f4* __restrict__ pe,
                const int* __restrict__ dia_len, int n_seg,
                f4* __restrict__ out, long n4) {
    __shared__ int ex[513];      // exclusive cumsum; seg s = rows [ex[s], ex[s+1])
    __shared__ int seg_lo[512];  // bucket b -> segment containing row b*64
    __shared__ int wsum[8];      // per-wave totals
    const int t    = threadIdx.x;
    const int lane = t & 63;
    const int wid  = t >> 6;

    // --- prologue: cumsum of dia_len via wave shuffle scan ---
    const int v = (t < n_seg) ? dia_len[t] : 0;
    int scan = v;
    #pragma unroll
    for (int off = 1; off < 64; off <<= 1) {
        const int u = __shfl_up(scan, off, 64);
        if (lane >= off) scan += u;
    }
    if (lane == 63) wsum[wid] = scan;
    __syncthreads();
    int pre = 0;
    #pragma unroll
    for (int w = 0; w < 8; ++w) pre += (w < wid) ? wsum[w] : 0;
    ex[t + 1] = scan + pre;
    if (t == 0) ex[0] = 0;
    __syncthreads();
    if (t < n_seg) {
        const int st = ex[t], en = ex[t + 1];
        for (int b = (st + 63) >> 6; (b << 6) < en; ++b) seg_lo[b] = t;
    }
    __syncthreads();

    const long stride = (long)gridDim.x * blockDim.x;
    long i = (long)blockIdx.x * blockDim.x + threadIdx.x;
    const int col = (int)(i & 255);   // constant per thread (stride % 256 == 0)

    #define PE_POS(ROW, P)                                            \
        int P;                                                        \
        {                                                             \
            int s_ = seg_lo[(ROW) >> 6];                              \
            while (ex[s_ + 1] <= (ROW)) ++s_;                         \
            P = (ROW) - ex[s_];                                       \
        }

    // Register-cached pe value; reload only when position changes.
    int p_cur = -1;
    f4 pv;
    #define PE_GET(P, B)                                              \
        if ((P) != p_cur) { p_cur = (P); pv = pe[((long)p_cur << 8) | col]; } \
        const f4 B = pv;

    for (; i + 3 * stride < n4; i += 4 * stride) {
        const long i0 = i, i1 = i + stride, i2 = i + 2 * stride, i3 = i + 3 * stride;
        const f4 a0 = x[i0], a1 = x[i1], a2 = x[i2], a3 = x[i3];
        const int r0 = (int)(i0 >> 8), r1 = (int)(i1 >> 8),
                  r2 = (int)(i2 >> 8), r3 = (int)(i3 >> 8);
        PE_POS(r0, p0) PE_POS(r1, p1) PE_POS(r2, p2) PE_POS(r3, p3)
        PE_GET(p0, b0)
        __builtin_nontemporal_store(a0 + b0, &out[i0]);
        PE_GET(p1, b1)
        __builtin_nontemporal_store(a1 + b1, &out[i1]);
        PE_GET(p2, b2)
        __builtin_nontemporal_store(a2 + b2, &out[i2]);
        PE_GET(p3, b3)
        __builtin_nontemporal_store(a3 + b3, &out[i3]);
    }
    for (; i < n4; i += stride) {
        const int row = (int)(i >> 8);
        PE_POS(row, p)
        PE_GET(p, b)
        const f4 a = x[i];
        __builtin_nontemporal_store(a + b, &out[i]);
    }
    #undef PE_POS
    #undef PE_GET
}

extern "C" void kernel_launch(void* const* d_in, const int* in_sizes, int n_in,
                              void* d_out, int out_size, void* d_ws, size_t ws_size,
                              hipStream_t stream) {
    const float* x  = (const float*)d_in[0];
    const float* pe = (const float*)d_in[1];
    const int*   dl = (const int*)d_in[2];

    const int n_seg = in_sizes[2];           // 512 (<= 512 for LDS tables)
    const long n4 = (long)out_size / 4;      // 8,388,608 f4 -> 16 per thread

    pe_fused_kernel<<<1024, 512, 0, stream>>>(
        (const f4*)x, (const f4*)pe, dl, n_seg, (f4*)d_out, n4);
}